// Round 2
// 1784.978 us; speedup vs baseline: 1.5218x; 1.5218x over previous
//
#include <hip/hip_runtime.h>

// RNN scan: h[t] = tanh(W_h h[t-1] + W_x x[t] + b), out = stacked h.
//  prep_kernel : transpose W_x -> wxT (fp32), extract bias, pack W_h -> f16
//                in TRANSPOSED-LANE cell layout (see below).
//  xin_gemm    : fp32 tiled GEMM writes u[t,b,h] = x.W_x^T + b INTO d_out.
//  rnn_scan    : 64 wgs (one per batch elem), 512 thr.
//                Lane layout per wave: lane = rl*8 + kl; kl owns k-slice
//                [64*kl,64*kl+64), rl indexes 8 rows; wave w owns rows
//                64w..64w+63 (row = 64w + 8i + rl, i=0..7).
//                h read COOPERATIVELY: 8 ds_read_b128 per thread per step
//                (vs 64 broadcast reads before) and reused across 8 rows in
//                registers -> 8x fewer LDS h instructions (the old kernel was
//                LDS-issue-bound on broadcasts).
//                Partial dots reduced across the 8 kl lanes by a pure-VALU
//                DPP butterfly (quad_perm xor1/xor2 + row_half_mirror).
//                W_h 64 cells/lane split: 32 in REGISTERS (128 VGPR),
//                16 in LDS (128 KiB), 16 STREAMED from L2 per step in four
//                4-cell chunks (32 VGPR of stream buffer, ~220 VGPR total —
//                stays under the 256 cap; 8-cell chunks risked spills).
//                h state double-buffered in LDS, skewed (uint4 idx g+(g>>3))
//                so 8-distinct-address slice reads are bank-conflict-free.

typedef _Float16 h2 __attribute__((ext_vector_type(2)));

#define T_STEPS 1024
#define B_SZ    64
#define NIN     128
#define NH      512
#define WCOLS   641        // NH + NIN + 1
// cell index c = j*8 + i (j = k-subgroup 0..7 within lane's slice, i = row idx)
// cells  0..31 (j=0..3): registers
// cells 32..47 (j=4..5): LDS
// cells 48..63 (j=6..7): streamed from L2 each step

__device__ __forceinline__ float fdot2_(h2 a, h2 b, float c) {
#if __has_builtin(__builtin_amdgcn_fdot2)
    return __builtin_amdgcn_fdot2(a, b, c, false);
#else
    return c + (float)a.x * (float)b.x + (float)a.y * (float)b.y;
#endif
}

__device__ __forceinline__ float dot8(uint4 wu, uint4 hu, float acc) {
    union { uint4 u; h2 h[4]; } w, hv;
    w.u = wu; hv.u = hu;
    acc = fdot2_(w.h[0], hv.h[0], acc);
    acc = fdot2_(w.h[1], hv.h[1], acc);
    acc = fdot2_(w.h[2], hv.h[2], acc);
    acc = fdot2_(w.h[3], hv.h[3], acc);
    return acc;
}

__device__ __forceinline__ float fast_tanh(float x) {
    // tanh(x) = 1 - 2/(exp2(x * 2/ln2) + 1); monotone-safe at +-inf
    float z = x * 2.8853900817779268f;
#if __has_builtin(__builtin_amdgcn_exp2f)
    float e = __builtin_amdgcn_exp2f(z);
#else
    float e = exp2f(z);
#endif
#if __has_builtin(__builtin_amdgcn_rcpf)
    return 1.f - 2.f * __builtin_amdgcn_rcpf(e + 1.f);
#else
    return 1.f - 2.f / (e + 1.f);
#endif
}

// cross-lane add via DPP (pure VALU, no LDS traffic)
template<int CTRL>
__device__ __forceinline__ float dpp_add(float x) {
    int y = __builtin_amdgcn_update_dpp(0, __builtin_bit_cast(int, x),
                                        CTRL, 0xF, 0xF, true);
    return x + __builtin_bit_cast(float, y);
}
// quad_perm(1,0,3,2) = 0xB1 (xor1), quad_perm(2,3,0,1) = 0x4E (xor2),
// row_half_mirror = 0x141 (i -> 7-i within 8; equals xor4 once quads uniform)

// ---------------- prep: weight reshuffle ----------------
__global__ void prep_kernel(const float* __restrict__ w_rec,
                            float* __restrict__ wxT,
                            float* __restrict__ bias,
                            uint4* __restrict__ Whpk) {
    int g = blockIdx.x * 256 + threadIdx.x;
    if (g < NIN * NH) {                               // wxT[i*512+h] = w_x[h][i]
        int i = g >> 9, h = g & (NH - 1);
        wxT[g] = w_rec[h * WCOLS + NH + i];
    } else if (g < NIN * NH + 64 * NH) {              // pack W_h cells to f16
        int m   = g - NIN * NH;                       // 0..32767
        int c   = m >> 9, tid = m & 511;
        int w   = tid >> 6, lane = tid & 63;
        int rl  = lane >> 3, kl = lane & 7;
        int i   = c & 7, j = c >> 3;
        int row = w * 64 + i * 8 + rl;
        int kg  = kl * 8 + j;                         // global k-group 0..63
        union { uint4 u; _Float16 f[8]; } pk;
#pragma unroll
        for (int e = 0; e < 8; ++e)
            pk.f[e] = (_Float16)w_rec[row * WCOLS + kg * 8 + e];
        Whpk[c * 512 + tid] = pk.u;
    } else if (g < NIN * NH + 64 * NH + NH) {         // bias
        int h = g - (NIN * NH + 64 * NH);
        bias[h] = w_rec[h * WCOLS + NH + NIN];
    }
}

// ---------------- xin GEMM: u = x @ W_x^T + b -> d_out ----------------
__global__ __launch_bounds__(256) void xin_gemm(const float* __restrict__ x,
                                                const float* __restrict__ wxT,
                                                const float* __restrict__ bias,
                                                float* __restrict__ out) {
    __shared__ float4 xl[128 * 8];    // [row][c4] 16 KiB
    __shared__ float4 wl[32 * 32];    // [i][c4]   16 KiB
    __shared__ float  bs[128];
    const int tid = threadIdx.x;
    const int tb0 = blockIdx.x * 128;
    const int hc0 = blockIdx.y * 128;
    if (tid < 128) bs[tid] = bias[hc0 + tid];
    const int tx = tid & 15, ty = tid >> 4;

    float acc[8][8];
#pragma unroll
    for (int r = 0; r < 8; ++r)
#pragma unroll
        for (int c = 0; c < 8; ++c) acc[r][c] = 0.f;

    for (int kc = 0; kc < 4; ++kc) {
        __syncthreads();
#pragma unroll
        for (int l = 0; l < 4; ++l) {                 // x chunk 128x32
            int idx = tid + 256 * l;
            int row = idx >> 3, c4 = idx & 7;
            xl[idx] = *(const float4*)(x + (long)(tb0 + row) * NIN + kc * 32 + c4 * 4);
        }
#pragma unroll
        for (int l = 0; l < 4; ++l) {                 // w chunk 32x128
            int idx = tid + 256 * l;
            int ii = idx >> 5, c4 = idx & 31;
            wl[idx] = *(const float4*)(wxT + (kc * 32 + ii) * NH + hc0 + c4 * 4);
        }
        __syncthreads();
#pragma unroll
        for (int i4 = 0; i4 < 8; ++i4) {
            float4 xv[8];
#pragma unroll
            for (int rr = 0; rr < 8; ++rr) xv[rr] = xl[(ty * 8 + rr) * 8 + i4];
#pragma unroll
            for (int j = 0; j < 4; ++j) {
                float4 w0 = wl[(i4 * 4 + j) * 32 + tx * 2];
                float4 w1 = wl[(i4 * 4 + j) * 32 + tx * 2 + 1];
#pragma unroll
                for (int rr = 0; rr < 8; ++rr) {
                    float xs = (j == 0) ? xv[rr].x : (j == 1) ? xv[rr].y
                             : (j == 2) ? xv[rr].z : xv[rr].w;
                    acc[rr][0] += xs * w0.x; acc[rr][1] += xs * w0.y;
                    acc[rr][2] += xs * w0.z; acc[rr][3] += xs * w0.w;
                    acc[rr][4] += xs * w1.x; acc[rr][5] += xs * w1.y;
                    acc[rr][6] += xs * w1.z; acc[rr][7] += xs * w1.w;
                }
            }
        }
    }
#pragma unroll
    for (int rr = 0; rr < 8; ++rr) {
        long row = tb0 + ty * 8 + rr;
        float4 o0, o1;
        o0.x = acc[rr][0] + bs[tx * 8 + 0]; o0.y = acc[rr][1] + bs[tx * 8 + 1];
        o0.z = acc[rr][2] + bs[tx * 8 + 2]; o0.w = acc[rr][3] + bs[tx * 8 + 3];
        o1.x = acc[rr][4] + bs[tx * 8 + 4]; o1.y = acc[rr][5] + bs[tx * 8 + 5];
        o1.z = acc[rr][6] + bs[tx * 8 + 6]; o1.w = acc[rr][7] + bs[tx * 8 + 7];
        *(float4*)(out + row * NH + hc0 + tx * 8)     = o0;
        *(float4*)(out + row * NH + hc0 + tx * 8 + 4) = o1;
    }
}

// ---------------- serial scan: one workgroup per batch element ----------------
__global__ __launch_bounds__(512, 2) void rnn_scan(float* __restrict__ out,
                                                   const float* __restrict__ h0,
                                                   const uint4* __restrict__ Whpk) {
    __shared__ uint4 Wl[16 * 512];   // cells 32..47, 128 KiB, per-lane-distinct
    __shared__ uint4 hh[2][72];      // double-buffered f16 h, skewed, 2.25 KiB

    const int tid  = threadIdx.x;
    const int b    = blockIdx.x;
    const int w    = tid >> 6;       // wave id (rows 64w..64w+63)
    const int lane = tid & 63;
    const int rl   = lane >> 3;      // row-group lane
    const int kl   = lane & 7;       // k-slice lane (k in [64*kl, 64*kl+64))

    // fill LDS W cells (j=4,5)
#pragma unroll
    for (int c = 0; c < 16; ++c) Wl[c * 512 + tid] = Whpk[(32 + c) * 512 + tid];

    // register cells (j=0..3): 128 VGPRs
    uint4 Wreg[32];
#pragma unroll
    for (int c = 0; c < 32; ++c) Wreg[c] = Whpk[c * 512 + tid];

    // h0 -> hh[0] (f16, skewed: group g at uint4 index g + (g>>3))
    {
        int g = tid >> 3, e = tid & 7;
        _Float16* p = (_Float16*)&hh[0][g + (g >> 3)];
        p[e] = (_Float16)h0[b * NH + tid];
    }
    __syncthreads();

    const int own = w * 64 + kl * 8 + rl;     // row this lane finalizes
    float* pu = out + (long)b * NH + own;     // u/h slot for (t, b, own)
    float u_cur = *pu;                        // u for t=0

    for (int t = 0; t < T_STEPS; ++t) {
        const uint4* hc = hh[t & 1];
        uint4 bufA[4], bufB[4];

        // issue stream chunk A (j=6, i=0..3) + next-u prefetch early
#pragma unroll
        for (int i = 0; i < 4; ++i) bufA[i] = Whpk[(48 + i) * 512 + tid];
        long stride = (t + 1 < T_STEPS) ? (long)B_SZ * NH : 0;
        float u_nxt = pu[stride];
        // issue stream chunk B (j=6, i=4..7)
#pragma unroll
        for (int i = 0; i < 4; ++i) bufB[i] = Whpk[(52 + i) * 512 + tid];

        // cooperative h read: this lane's 8 k-groups (8*kl+j), skewed idx 9*kl+j
        uint4 hs[8];
#pragma unroll
        for (int j = 0; j < 8; ++j) hs[j] = hc[9 * kl + j];

        float acc[8];
#pragma unroll
        for (int i = 0; i < 8; ++i) acc[i] = 0.f;

        // register cells j=0..3 (32 dot8) — covers stream-A latency
#pragma unroll
        for (int j = 0; j < 4; ++j)
#pragma unroll
            for (int i = 0; i < 8; ++i)
                acc[i] = dot8(Wreg[j * 8 + i], hs[j], acc[i]);

        // consume A (j=6, rows 0..3); reissue into bufA (j=7, rows 0..3)
#pragma unroll
        for (int i = 0; i < 4; ++i) acc[i] = dot8(bufA[i], hs[6], acc[i]);
#pragma unroll
        for (int i = 0; i < 4; ++i) bufA[i] = Whpk[(56 + i) * 512 + tid];

        // consume B (j=6, rows 4..7); reissue into bufB (j=7, rows 4..7)
#pragma unroll
        for (int i = 0; i < 4; ++i) acc[4 + i] = dot8(bufB[i], hs[6], acc[4 + i]);
#pragma unroll
        for (int i = 0; i < 4; ++i) bufB[i] = Whpk[(60 + i) * 512 + tid];

        // LDS cells j=4,5 (per-lane-distinct, full-bandwidth reads)
#pragma unroll
        for (int j = 0; j < 2; ++j)
#pragma unroll
            for (int i = 0; i < 8; ++i)
                acc[i] = dot8(Wl[(j * 8 + i) * 512 + tid], hs[4 + j], acc[i]);

        // consume second stream pair (j=7)
#pragma unroll
        for (int i = 0; i < 4; ++i) acc[i] = dot8(bufA[i], hs[7], acc[i]);
#pragma unroll
        for (int i = 0; i < 4; ++i) acc[4 + i] = dot8(bufB[i], hs[7], acc[4 + i]);

        // reduce across the 8 kl lanes (pure-VALU DPP butterfly)
#pragma unroll
        for (int i = 0; i < 8; ++i) {
            acc[i] = dpp_add<0xB1>(acc[i]);    // xor1: quad_perm(1,0,3,2)
            acc[i] = dpp_add<0x4E>(acc[i]);    // xor2: quad_perm(2,3,0,1)
            acc[i] = dpp_add<0x141>(acc[i]);   // xor4: row_half_mirror
        }

        // lane owns row 64w + 8*kl + rl  ->  select acc[kl]
        float a01 = (kl & 1) ? acc[1] : acc[0];
        float a23 = (kl & 1) ? acc[3] : acc[2];
        float a45 = (kl & 1) ? acc[5] : acc[4];
        float a67 = (kl & 1) ? acc[7] : acc[6];
        float b03 = (kl & 2) ? a23 : a01;
        float b47 = (kl & 2) ? a67 : a45;
        float sel = (kl & 4) ? b47 : b03;

        float hnew = fast_tanh(sel + u_cur);
        u_cur = u_nxt;
        *pu = hnew;                            // fp32 output (in place)
        pu += B_SZ * NH;

        // publish f16 state: global group 8w+kl, elem rl, skewed idx 9w+kl
        {
            _Float16* p = (_Float16*)&hh[(t + 1) & 1][9 * w + kl];
            p[rl] = (_Float16)hnew;
        }
        __syncthreads();   // writes to hh[(t+1)&1] visible; reads of hc done
    }
}

extern "C" void kernel_launch(void* const* d_in, const int* in_sizes, int n_in,
                              void* d_out, int out_size, void* d_ws, size_t ws_size,
                              hipStream_t stream) {
    const float* x     = (const float*)d_in[0];   // (1024,64,128)
    const float* h0    = (const float*)d_in[1];   // (64,512)
    const float* w_rec = (const float*)d_in[2];   // (512,641)
    float* out = (float*)d_out;                   // (1024,64,512)

    // workspace layout: wxT (256 KiB) | bias (2 KiB) | Whpk f16 (512 KiB)
    float* wxT  = (float*)d_ws;
    float* bias = wxT + NIN * NH;
    uint4* Whpk = (uint4*)((char*)d_ws + (NIN * NH + NH) * sizeof(float)); // 16B aligned

    prep_kernel<<<387, 256, 0, stream>>>(w_rec, wxT, bias, Whpk);

    dim3 gA(T_STEPS * B_SZ / 128, NH / 128);      // 512 x 4
    xin_gemm<<<gA, 256, 0, stream>>>(x, wxT, bias, out);

    rnn_scan<<<B_SZ, NH, 0, stream>>>(out, h0, Whpk);
}